// Round 4
// baseline (14.079 us; speedup 1.0000x reference)
//
#include <hip/hip_runtime.h>
#include <math.h>

typedef _Float16 f16;
typedef _Float16 f16x2 __attribute__((ext_vector_type(2)));
typedef _Float16 f16x4 __attribute__((ext_vector_type(4)));

constexpr int   MAX_STEPS = 16;
constexpr float STEP_SIZE = 0.001f;
constexpr float BG        = 1.0f;
constexpr int   NVOX      = 64;    // 4^3 leaf-resolution voxels
constexpr int   VOX_H     = 28;    // halves per record (56 B; gcd(14,32)=2 is b64-aligned optimum)
constexpr float NLOG2E    = -1.4426950408889634f;
constexpr float BIGT      = 2.4e8f;   // > any real boundary t; < 1e9*len

__device__ __forceinline__ float fdot2(unsigned w, f16x2 s, float acc) {
#if __has_builtin(__builtin_amdgcn_fdot2)
    return __builtin_amdgcn_fdot2(__builtin_bit_cast(f16x2, w), s, acc, false);
#else
    f16x2 a = __builtin_bit_cast(f16x2, w);
    return acc + (float)a.x * (float)s.x + (float)a.y * (float)s.y;
#endif
}

__device__ __forceinline__ float fexp2(float x) {
#if __has_builtin(__builtin_amdgcn_exp2f)
    return __builtin_amdgcn_exp2f(x);
#else
    return exp2f(x);
#endif
}

// Geometry in GLOBAL t-units (bit-exact vs reference local-unit DDA: all
// rescalings are by powers of two, which commute with fp rounding).
#define GEOM(TC, LIDX, DTV)                                                  \
  {                                                                          \
    float px = fmaf((TC), dnx, otx);                                         \
    float py = fmaf((TC), dny, oty);                                         \
    float pz = fmaf((TC), dnz, otz);                                         \
    float pcx = fminf(fmaxf(px, 0.0f), 0.999999f);                           \
    float pcy = fminf(fmaxf(py, 0.0f), 0.999999f);                           \
    float pcz = fminf(fmaxf(pz, 0.0f), 0.999999f);                           \
    int vx = (int)(pcx * 4.0f);                                              \
    int vy = (int)(pcy * 4.0f);                                              \
    int vz = (int)(pcz * 4.0f);                                              \
    (LIDX) = (vx << 4) | (vy << 2) | vz;                                     \
    bool d2 = (d2mask >> (LIDX)) & 1ull;                                     \
    float lenv = d2 ? 0.25f : 0.5f;                                          \
    int   shf  = d2 ? 0 : 1;                                                 \
    float T1x = fmaf((float)(vx >> shf), lenv, -px) * ivx;                   \
    float T1y = fmaf((float)(vy >> shf), lenv, -py) * ivy;                   \
    float T1z = fmaf((float)(vz >> shf), lenv, -pz) * ivz;                   \
    float T2x = T1x + (d2 ? ivqx : ivhx);                                    \
    float T2y = T1y + (d2 ? ivqy : ivhy);                                    \
    float T2z = T1z + (d2 ? ivqz : ivhz);                                    \
    float m = fmaxf(fmaxf(fminf(T1x,T2x), fminf(T1y,T2y)),                   \
                    fmaxf(fminf(T1z,T2z), 0.0f));                            \
    float M = fminf(fminf(fmaxf(T1x,T2x), fmaxf(T1y,T2y)),                   \
                    fminf(fmaxf(T1z,T2z), BIGT));                            \
    (DTV) = (M - m) + STEP_SIZE;                                             \
  }

#define PREF(LI, Q0,Q1,Q2,Q3,Q4,Q5,Q6)                                       \
  {                                                                          \
    const uint2* _r = (const uint2*)(s_vh + (LI) * VOX_H);                   \
    Q0=_r[0]; Q1=_r[1]; Q2=_r[2]; Q3=_r[3]; Q4=_r[4]; Q5=_r[5]; Q6=_r[6];    \
  }

// Shade step s from A regs; advance geometry to s+1 and prefetch into B regs.
#define STEP(QA0,QA1,QA2,QA3,QA4,QA5,QA6, QB0,QB1,QB2,QB3,QB4,QB5,QB6)       \
  {                                                                          \
    bool act = t_cur < tmax;                                                 \
    float t_next = act ? t_cur + dtc : t_cur;                                \
    int lin; float dtn;                                                      \
    GEOM(t_next, lin, dtn);                                                  \
    PREF(lin, QB0,QB1,QB2,QB3,QB4,QB5,QB6);                                  \
    unsigned D0=QA0.x, D1=QA0.y, D2=QA1.x, D3=QA1.y, D4=QA2.x, D5=QA2.y,     \
             D6=QA3.x, D7=QA3.y, D8=QA4.x, D9=QA4.y, D10=QA5.x, D11=QA5.y,   \
             D12=QA6.x, D13=QA6.y;                                           \
    float a0=0.f, a1=0.f, a2=0.f;   /* dots pre-scaled by -log2e */          \
    a0=fdot2(D0,shA0,a0); a0=fdot2(D1,shA1,a0); a0=fdot2(D2,shA2,a0);        \
    a0=fdot2(D3,shA3,a0); a0=fdot2(D4,shA4,a0);                              \
    a1=fdot2(D4,shB0,a1); a1=fdot2(D5,shB1,a1); a1=fdot2(D6,shB2,a1);        \
    a1=fdot2(D7,shB3,a1); a1=fdot2(D8,shB4,a1);                              \
    a2=fdot2(D9,shA0,a2); a2=fdot2(D10,shA1,a2); a2=fdot2(D11,shA2,a2);      \
    a2=fdot2(D12,shA3,a2); a2=fdot2(D13,shA4,a2);                            \
    f16x2 lastp = __builtin_bit_cast(f16x2, D13);                            \
    float sigma = fmaxf((float)lastp.y, 0.0f);                               \
    float att = fexp2(katt2 * dtc * sigma);                                  \
    float la  = light * att;                                                 \
    float w   = act ? (light - la) : 0.0f;                                   \
    float r0 = __builtin_amdgcn_rcpf(1.0f + fexp2(a0));                      \
    float r1 = __builtin_amdgcn_rcpf(1.0f + fexp2(a1));                      \
    float r2 = __builtin_amdgcn_rcpf(1.0f + fexp2(a2));                      \
    o0 = fmaf(w, r0, o0);                                                    \
    o1 = fmaf(w, r1, o1);                                                    \
    o2 = fmaf(w, r2, o2);                                                    \
    light = act ? la : light;                                                \
    t_cur = t_next;                                                          \
    dtc = dtn;                                                               \
  }

__global__ __launch_bounds__(512, 4) void vr_kernel(
    const float* __restrict__ origins,
    const float* __restrict__ dirs,
    const float* __restrict__ viewdirs,
    const float* __restrict__ data,
    const int*   __restrict__ child,
    const float* __restrict__ offset,
    const float* __restrict__ invradius_p,
    float* __restrict__ out,
    int B)
{
    __shared__ f16 s_vh[NVOX * VOX_H];   // 3584 B

    const int t0   = threadIdx.x;
    const int lane = t0 & 63;

    // Wave-uniform 64-bit mask: bit v = 1 if voxel v resolves at depth 2.
    unsigned long long d2mask;
    {
        int vx = lane >> 4, vy = (lane >> 2) & 3, vz = lane & 3;
        int e0 = ((vx >> 1) << 2) | ((vy >> 1) << 1) | (vz >> 1);
        d2mask = __ballot(child[e0] != 0);
    }

    // Stage voxel records: 448 float4 items, one per thread (8 threads/voxel,
    // 7 active). No LDS round-trip, single barrier.
    {
        int v = t0 >> 3, s = t0 & 7;
        if (v < NVOX && s < 7) {
            int vx = v >> 4, vy = (v >> 2) & 3, vz = v & 3;
            int e0  = ((vx >> 1) << 2) | ((vy >> 1) << 1) | (vz >> 1);
            int ch  = child[e0];
            int fe  = ch ? ch * 8 + (((vx & 1) << 2) | ((vy & 1) << 1) | (vz & 1))
                         : e0;
            float4 w = *reinterpret_cast<const float4*>(data + fe * 28 + s * 4);
            f16x4 p; p.x=(f16)w.x; p.y=(f16)w.y; p.z=(f16)w.z; p.w=(f16)w.w;
            *reinterpret_cast<f16x4*>(s_vh + v * VOX_H + s * 4) = p;  // 8-B aligned
        }
    }
    __syncthreads();

    int tid = blockIdx.x * 512 + t0;
    if (tid >= B) return;

    float ox = origins[tid*3+0], oy = origins[tid*3+1], oz = origins[tid*3+2];
    float dx = dirs[tid*3+0],    dy = dirs[tid*3+1],    dz = dirs[tid*3+2];
    float vdx = viewdirs[tid*3+0], vdy = viewdirs[tid*3+1], vdz = viewdirs[tid*3+2];
    float invr = invradius_p[0];
    float otx = offset[0] + ox * invr;
    float oty = offset[1] + oy * invr;
    float otz = offset[2] + oz * invr;

    // SH-9 basis pre-scaled by -log2e (so sigmoid = rcp(1+exp2(dot))).
    float sh[9];
    {
        const float C0 = 0.28209479177387814f;
        const float C1 = 0.4886025119029199f;
        sh[0] = C0;
        sh[1] = -C1 * vdy;
        sh[2] =  C1 * vdz;
        sh[3] = -C1 * vdx;
        sh[4] =  1.0925484305920792f * vdx * vdy;
        sh[5] = -1.0925484305920792f * vdy * vdz;
        sh[6] =  0.31539156525252005f * (2.0f*vdz*vdz - vdx*vdx - vdy*vdy);
        sh[7] = -1.0925484305920792f * vdx * vdz;
        sh[8] =  0.5462742152960396f * (vdx*vdx - vdy*vdy);
        #pragma unroll
        for (int k = 0; k < 9; ++k) sh[k] *= NLOG2E;
    }
    f16x2 shA0 = f16x2{(f16)sh[0], (f16)sh[1]};
    f16x2 shA1 = f16x2{(f16)sh[2], (f16)sh[3]};
    f16x2 shA2 = f16x2{(f16)sh[4], (f16)sh[5]};
    f16x2 shA3 = f16x2{(f16)sh[6], (f16)sh[7]};
    f16x2 shA4 = f16x2{(f16)sh[8], (f16)0.0f};
    f16x2 shB0 = f16x2{(f16)0.0f,  (f16)sh[0]};
    f16x2 shB1 = f16x2{(f16)sh[1], (f16)sh[2]};
    f16x2 shB2 = f16x2{(f16)sh[3], (f16)sh[4]};
    f16x2 shB3 = f16x2{(f16)sh[5], (f16)sh[6]};
    f16x2 shB4 = f16x2{(f16)sh[7], (f16)sh[8]};

    float nrm = sqrtf(dx*dx + dy*dy + dz*dz);
    float dnx = dx / nrm, dny = dy / nrm, dnz = dz / nrm;
    float ivx = 1.0f / (dnx + 1e-9f);
    float ivy = 1.0f / (dny + 1e-9f);
    float ivz = 1.0f / (dnz + 1e-9f);
    float ivqx = ivx * 0.25f, ivqy = ivy * 0.25f, ivqz = ivz * 0.25f; // exact
    float ivhx = ivx * 0.5f,  ivhy = ivy * 0.5f,  ivhz = ivz * 0.5f;  // exact

    float t_cur, tmax;
    {
        float t1x = -otx * ivx, t2x = t1x + ivx;
        float t1y = -oty * ivy, t2y = t1y + ivy;
        float t1z = -otz * ivz, t2z = t1z + ivz;
        float mn = fmaxf(fmaxf(fminf(t1x,t2x), fminf(t1y,t2y)), fminf(t1z,t2z));
        float mx = fminf(fminf(fmaxf(t1x,t2x), fmaxf(t1y,t2y)), fmaxf(t1z,t2z));
        t_cur = fmaxf(mn, 0.0f);
        tmax  = fminf(mx, 1000000000.0f);
    }

    const float katt2 = (1.0f / invr) * NLOG2E;   // -delta_scale*log2e
    float light = 1.0f;
    float o0 = 0.0f, o1 = 0.0f, o2 = 0.0f;

    uint2 A0,A1,A2,A3,A4,A5,A6, B0,B1,B2,B3,B4,B5,B6;
    int li0; float dtc;
    GEOM(t_cur, li0, dtc);
    PREF(li0, A0,A1,A2,A3,A4,A5,A6);

    #pragma unroll 1
    for (int s = 0; s < MAX_STEPS; s += 2) {
        if (!__any(t_cur < tmax)) break;
        STEP(A0,A1,A2,A3,A4,A5,A6, B0,B1,B2,B3,B4,B5,B6);
        STEP(B0,B1,B2,B3,B4,B5,B6, A0,A1,A2,A3,A4,A5,A6);
    }

    out[tid*3+0] = fmaf(light, BG, o0);
    out[tid*3+1] = fmaf(light, BG, o1);
    out[tid*3+2] = fmaf(light, BG, o2);
}

extern "C" void kernel_launch(void* const* d_in, const int* in_sizes, int n_in,
                              void* d_out, int out_size, void* d_ws, size_t ws_size,
                              hipStream_t stream) {
    const float* origins  = (const float*)d_in[0];
    const float* dirs     = (const float*)d_in[1];
    const float* viewdirs = (const float*)d_in[2];
    const float* data     = (const float*)d_in[3];
    const int*   child    = (const int*)d_in[4];
    const float* offset   = (const float*)d_in[5];
    const float* invrad   = (const float*)d_in[6];
    float* out = (float*)d_out;
    int B = in_sizes[0] / 3;
    int block = 512;
    int grid = (B + block - 1) / block;
    vr_kernel<<<grid, block, 0, stream>>>(origins, dirs, viewdirs, data, child,
                                          offset, invrad, out, B);
}

// Round 5
// 13.375 us; speedup vs baseline: 1.0526x; 1.0526x over previous
//
#include <hip/hip_runtime.h>
#include <math.h>

typedef _Float16 f16;
typedef _Float16 f16x2 __attribute__((ext_vector_type(2)));

constexpr int   MAX_STEPS = 16;
constexpr float STEP_SIZE = 0.001f;
constexpr float BG        = 1.0f;
constexpr int   NVOX      = 64;    // 4^3 leaf-resolution voxels
constexpr int   VOX_DW    = 15;    // dwords/record: 60-B stride, gcd(15,32)=1 -> all 32 banks
constexpr float NLOG2E    = -1.4426950408889634f;
constexpr float BIGT      = 2.4e8f;   // > any real boundary t; < 1e9*len

__device__ __forceinline__ float fdot2(unsigned w, f16x2 s, float acc) {
#if __has_builtin(__builtin_amdgcn_fdot2)
    return __builtin_amdgcn_fdot2(__builtin_bit_cast(f16x2, w), s, acc, false);
#else
    f16x2 a = __builtin_bit_cast(f16x2, w);
    return acc + (float)a.x * (float)s.x + (float)a.y * (float)s.y;
#endif
}

__device__ __forceinline__ float fexp2(float x) {
#if __has_builtin(__builtin_amdgcn_exp2f)
    return __builtin_amdgcn_exp2f(x);
#else
    return exp2f(x);
#endif
}

// Geometry in GLOBAL t-units (bit-exact vs reference local-unit DDA: all
// rescalings are by powers of two, which commute with fp rounding).
#define GEOM(TC, LIDX, DTV)                                                  \
  {                                                                          \
    float px = fmaf((TC), dnx, otx);                                         \
    float py = fmaf((TC), dny, oty);                                         \
    float pz = fmaf((TC), dnz, otz);                                         \
    float pcx = fminf(fmaxf(px, 0.0f), 0.999999f);                           \
    float pcy = fminf(fmaxf(py, 0.0f), 0.999999f);                           \
    float pcz = fminf(fmaxf(pz, 0.0f), 0.999999f);                           \
    int vx = (int)(pcx * 4.0f);                                              \
    int vy = (int)(pcy * 4.0f);                                              \
    int vz = (int)(pcz * 4.0f);                                              \
    (LIDX) = (vx << 4) | (vy << 2) | vz;                                     \
    bool d2 = (d2mask >> (LIDX)) & 1ull;                                     \
    float lenv = d2 ? 0.25f : 0.5f;                                          \
    int   shf  = d2 ? 0 : 1;                                                 \
    float T1x = fmaf((float)(vx >> shf), lenv, -px) * ivx;                   \
    float T1y = fmaf((float)(vy >> shf), lenv, -py) * ivy;                   \
    float T1z = fmaf((float)(vz >> shf), lenv, -pz) * ivz;                   \
    float T2x = T1x + (d2 ? ivqx : ivhx);                                    \
    float T2y = T1y + (d2 ? ivqy : ivhy);                                    \
    float T2z = T1z + (d2 ? ivqz : ivhz);                                    \
    float m = fmaxf(fmaxf(fminf(T1x,T2x), fminf(T1y,T2y)),                   \
                    fmaxf(fminf(T1z,T2z), 0.0f));                            \
    float M = fminf(fminf(fmaxf(T1x,T2x), fmaxf(T1y,T2y)),                   \
                    fminf(fmaxf(T1z,T2z), BIGT));                            \
    (DTV) = (M - m) + STEP_SIZE;                                             \
  }

// 14 dword LDS reads from a 4-B-aligned (not 8-B) base -> compiler must emit
// ds_read2_b32 / ds_read_b32 (dword-granular: full 32-bank conflict spread).
#define PREF(LI, P)                                                          \
  {                                                                          \
    const unsigned* _r = s_vh32 + (LI) * VOX_DW;                             \
    P##0=_r[0];   P##1=_r[1];   P##2=_r[2];   P##3=_r[3];                    \
    P##4=_r[4];   P##5=_r[5];   P##6=_r[6];   P##7=_r[7];                    \
    P##8=_r[8];   P##9=_r[9];   P##10=_r[10]; P##11=_r[11];                  \
    P##12=_r[12]; P##13=_r[13];                                              \
  }

// Shade step s from PA regs; advance geometry to s+1 and prefetch into PB,
// exec-masked to lanes that will actually be active (conflict reduction).
#define STEP(PA, PB)                                                         \
  {                                                                          \
    bool act = t_cur < tmax;                                                 \
    if (!__any(act)) break;                                                  \
    float t_next = act ? t_cur + dtc : t_cur;                                \
    int lin; float dtn;                                                      \
    GEOM(t_next, lin, dtn);                                                  \
    if (t_next < tmax) { PREF(lin, PB); }                                    \
    float a0=0.f, a1=0.f, a2=0.f;   /* dots pre-scaled by -log2e */          \
    a0=fdot2(PA##0,shA0,a0); a0=fdot2(PA##1,shA1,a0);                        \
    a0=fdot2(PA##2,shA2,a0); a0=fdot2(PA##3,shA3,a0);                        \
    a0=fdot2(PA##4,shA4,a0);                                                 \
    a1=fdot2(PA##4,shB0,a1); a1=fdot2(PA##5,shB1,a1);                        \
    a1=fdot2(PA##6,shB2,a1); a1=fdot2(PA##7,shB3,a1);                        \
    a1=fdot2(PA##8,shB4,a1);                                                 \
    a2=fdot2(PA##9,shA0,a2); a2=fdot2(PA##10,shA1,a2);                       \
    a2=fdot2(PA##11,shA2,a2); a2=fdot2(PA##12,shA3,a2);                      \
    a2=fdot2(PA##13,shA4,a2);                                                \
    f16x2 lastp = __builtin_bit_cast(f16x2, PA##13);                         \
    float sigma = fmaxf((float)lastp.y, 0.0f);                               \
    float att = fexp2(katt2 * dtc * sigma);                                  \
    float la  = light * att;                                                 \
    float w   = act ? (light - la) : 0.0f;                                   \
    float r0 = __builtin_amdgcn_rcpf(1.0f + fexp2(a0));                      \
    float r1 = __builtin_amdgcn_rcpf(1.0f + fexp2(a1));                      \
    float r2 = __builtin_amdgcn_rcpf(1.0f + fexp2(a2));                      \
    o0 = fmaf(w, r0, o0);                                                    \
    o1 = fmaf(w, r1, o1);                                                    \
    o2 = fmaf(w, r2, o2);                                                    \
    light = act ? la : light;                                                \
    t_cur = t_next;                                                          \
    dtc = dtn;                                                               \
  }

__global__ __launch_bounds__(512, 4) void vr_kernel(
    const float* __restrict__ origins,
    const float* __restrict__ dirs,
    const float* __restrict__ viewdirs,
    const float* __restrict__ data,
    const int*   __restrict__ child,
    const float* __restrict__ offset,
    const float* __restrict__ invradius_p,
    float* __restrict__ out,
    int B)
{
    __shared__ unsigned s_vh32[NVOX * VOX_DW];   // 3840 B

    const int t0   = threadIdx.x;
    const int lane = t0 & 63;

    // Wave-uniform 64-bit mask: bit v = 1 if voxel v resolves at depth 2.
    unsigned long long d2mask;
    {
        int vx = lane >> 4, vy = (lane >> 2) & 3, vz = lane & 3;
        int e0 = ((vx >> 1) << 2) | ((vy >> 1) << 1) | (vz >> 1);
        d2mask = __ballot(child[e0] != 0);
    }

    // Stage fp16 voxel records at 15-dword stride (8 threads/voxel, 7 active).
    {
        int v = t0 >> 3, s = t0 & 7;
        if (v < NVOX && s < 7) {
            int vx = v >> 4, vy = (v >> 2) & 3, vz = v & 3;
            int e0  = ((vx >> 1) << 2) | ((vy >> 1) << 1) | (vz >> 1);
            int ch  = child[e0];
            int fe  = ch ? ch * 8 + (((vx & 1) << 2) | ((vy & 1) << 1) | (vz & 1))
                         : e0;
            float4 w = *reinterpret_cast<const float4*>(data + fe * 28 + s * 4);
            f16x2 p0; p0.x = (f16)w.x; p0.y = (f16)w.y;
            f16x2 p1; p1.x = (f16)w.z; p1.y = (f16)w.w;
            s_vh32[v * VOX_DW + 2*s]     = __builtin_bit_cast(unsigned, p0);
            s_vh32[v * VOX_DW + 2*s + 1] = __builtin_bit_cast(unsigned, p1);
        }
    }
    __syncthreads();

    int tid = blockIdx.x * 512 + t0;
    if (tid >= B) return;

    float ox = origins[tid*3+0], oy = origins[tid*3+1], oz = origins[tid*3+2];
    float dx = dirs[tid*3+0],    dy = dirs[tid*3+1],    dz = dirs[tid*3+2];
    float vdx = viewdirs[tid*3+0], vdy = viewdirs[tid*3+1], vdz = viewdirs[tid*3+2];
    float invr = invradius_p[0];
    float otx = offset[0] + ox * invr;
    float oty = offset[1] + oy * invr;
    float otz = offset[2] + oz * invr;

    // SH-9 basis pre-scaled by -log2e (so sigmoid = rcp(1+exp2(dot))).
    float sh[9];
    {
        const float C0 = 0.28209479177387814f;
        const float C1 = 0.4886025119029199f;
        sh[0] = C0;
        sh[1] = -C1 * vdy;
        sh[2] =  C1 * vdz;
        sh[3] = -C1 * vdx;
        sh[4] =  1.0925484305920792f * vdx * vdy;
        sh[5] = -1.0925484305920792f * vdy * vdz;
        sh[6] =  0.31539156525252005f * (2.0f*vdz*vdz - vdx*vdx - vdy*vdy);
        sh[7] = -1.0925484305920792f * vdx * vdz;
        sh[8] =  0.5462742152960396f * (vdx*vdx - vdy*vdy);
        #pragma unroll
        for (int k = 0; k < 9; ++k) sh[k] *= NLOG2E;
    }
    f16x2 shA0 = f16x2{(f16)sh[0], (f16)sh[1]};
    f16x2 shA1 = f16x2{(f16)sh[2], (f16)sh[3]};
    f16x2 shA2 = f16x2{(f16)sh[4], (f16)sh[5]};
    f16x2 shA3 = f16x2{(f16)sh[6], (f16)sh[7]};
    f16x2 shA4 = f16x2{(f16)sh[8], (f16)0.0f};
    f16x2 shB0 = f16x2{(f16)0.0f,  (f16)sh[0]};
    f16x2 shB1 = f16x2{(f16)sh[1], (f16)sh[2]};
    f16x2 shB2 = f16x2{(f16)sh[3], (f16)sh[4]};
    f16x2 shB3 = f16x2{(f16)sh[5], (f16)sh[6]};
    f16x2 shB4 = f16x2{(f16)sh[7], (f16)sh[8]};

    float nrm = sqrtf(dx*dx + dy*dy + dz*dz);
    float dnx = dx / nrm, dny = dy / nrm, dnz = dz / nrm;
    float ivx = 1.0f / (dnx + 1e-9f);
    float ivy = 1.0f / (dny + 1e-9f);
    float ivz = 1.0f / (dnz + 1e-9f);
    float ivqx = ivx * 0.25f, ivqy = ivy * 0.25f, ivqz = ivz * 0.25f; // exact
    float ivhx = ivx * 0.5f,  ivhy = ivy * 0.5f,  ivhz = ivz * 0.5f;  // exact

    float t_cur, tmax;
    {
        float t1x = -otx * ivx, t2x = t1x + ivx;
        float t1y = -oty * ivy, t2y = t1y + ivy;
        float t1z = -otz * ivz, t2z = t1z + ivz;
        float mn = fmaxf(fmaxf(fminf(t1x,t2x), fminf(t1y,t2y)), fminf(t1z,t2z));
        float mx = fminf(fminf(fmaxf(t1x,t2x), fmaxf(t1y,t2y)), fmaxf(t1z,t2z));
        t_cur = fmaxf(mn, 0.0f);
        tmax  = fminf(mx, 1000000000.0f);
    }

    const float katt2 = (1.0f / invr) * NLOG2E;   // -delta_scale*log2e
    float light = 1.0f;
    float o0 = 0.0f, o1 = 0.0f, o2 = 0.0f;

    unsigned A0,A1,A2,A3,A4,A5,A6,A7,A8,A9,A10,A11,A12,A13;
    // B zero-init: lanes masked off at step 1 shade zeros (w=0, no NaN).
    unsigned B0=0,B1=0,B2=0,B3=0,B4=0,B5=0,B6=0,B7=0,B8=0,B9=0,B10=0,B11=0,
             B12=0,B13=0;
    int li0; float dtc;
    GEOM(t_cur, li0, dtc);
    PREF(li0, A);

    #pragma unroll 1
    for (int s = 0; s < MAX_STEPS; s += 2) {
        STEP(A, B);
        STEP(B, A);
    }

    out[tid*3+0] = fmaf(light, BG, o0);
    out[tid*3+1] = fmaf(light, BG, o1);
    out[tid*3+2] = fmaf(light, BG, o2);
}

extern "C" void kernel_launch(void* const* d_in, const int* in_sizes, int n_in,
                              void* d_out, int out_size, void* d_ws, size_t ws_size,
                              hipStream_t stream) {
    const float* origins  = (const float*)d_in[0];
    const float* dirs     = (const float*)d_in[1];
    const float* viewdirs = (const float*)d_in[2];
    const float* data     = (const float*)d_in[3];
    const int*   child    = (const int*)d_in[4];
    const float* offset   = (const float*)d_in[5];
    const float* invrad   = (const float*)d_in[6];
    float* out = (float*)d_out;
    int B = in_sizes[0] / 3;
    int block = 512;
    int grid = (B + block - 1) / block;
    vr_kernel<<<grid, block, 0, stream>>>(origins, dirs, viewdirs, data, child,
                                          offset, invrad, out, B);
}